// Round 3
// baseline (567.478 us; speedup 1.0000x reference)
//
#include <hip/hip_runtime.h>

typedef unsigned short u16;
typedef unsigned int u32;
typedef __attribute__((ext_vector_type(8))) short short8;
typedef __attribute__((ext_vector_type(4))) float f32x4;

__device__ __forceinline__ float bl(u32 u){ return __builtin_bit_cast(float, u << 16); }
__device__ __forceinline__ float bh(u32 u){ return __builtin_bit_cast(float, u & 0xffff0000u); }
__device__ __forceinline__ float bf2f(u16 h){ return __builtin_bit_cast(float, ((u32)h) << 16); }
__device__ __forceinline__ u16 f2bf(float f){
  u32 u = __builtin_bit_cast(u32, f);
  u32 r = u + 0x7fffu + ((u >> 16) & 1u);
  return (u16)(r >> 16);
}

// ------- Kernel 0: x fp32 [b][c][hw] -> XTh/XTl bf16 hi/lo split, pixel-major [pix][c] -------
__global__ __launch_bounds__(256) void split_in(const float* __restrict__ x,
                                                u16* __restrict__ XTh,
                                                u16* __restrict__ XTl)
{
  __shared__ float tile[64 * 68];
  int t = threadIdx.x;
  int hw0 = blockIdx.x * 64, c0 = blockIdx.y * 64, b = blockIdx.z;
  {
    int cl = t >> 2, seg = (t & 3) * 16;
    const float* src = x + (b * 256 + c0 + cl) * 4096 + hw0 + seg;
    float4 v0 = ((const float4*)src)[0];
    float4 v1 = ((const float4*)src)[1];
    float4 v2 = ((const float4*)src)[2];
    float4 v3 = ((const float4*)src)[3];
    float* d = tile + cl * 68 + seg;
    ((float4*)d)[0] = v0; ((float4*)d)[1] = v1;
    ((float4*)d)[2] = v2; ((float4*)d)[3] = v3;
  }
  __syncthreads();
  {
    int hwl = t >> 2, cs = (t & 3) * 16;
    u32 ph[8], pl[8];
    #pragma unroll
    for (int e = 0; e < 8; ++e) {
      float v0 = tile[(cs + 2 * e) * 68 + hwl];
      float v1 = tile[(cs + 2 * e + 1) * 68 + hwl];
      u16 h0 = f2bf(v0), h1 = f2bf(v1);
      u16 l0 = f2bf(v0 - bf2f(h0)), l1 = f2bf(v1 - bf2f(h1));
      ph[e] = (u32)h0 | ((u32)h1 << 16);
      pl[e] = (u32)l0 | ((u32)l1 << 16);
    }
    int off = (b * 4096 + hw0 + hwl) * 256 + c0 + cs;
    *(uint4*)(XTh + off)     = make_uint4(ph[0], ph[1], ph[2], ph[3]);
    *(uint4*)(XTh + off + 8) = make_uint4(ph[4], ph[5], ph[6], ph[7]);
    *(uint4*)(XTl + off)     = make_uint4(pl[0], pl[1], pl[2], pl[3]);
    *(uint4*)(XTl + off + 8) = make_uint4(pl[4], pl[5], pl[6], pl[7]);
  }
}

// ------- Kernel 1: q/k via 3-pass split-bf16 MFMA, v via 1-pass bf16. Output c-major [o][pix]. -------
#define LSTR 40
__global__ __launch_bounds__(256) void qkv_gemm(const u16* __restrict__ XTh,
                                                const u16* __restrict__ XTl,
                                                const float* __restrict__ w1,
                                                const float* __restrict__ w2,
                                                const float* __restrict__ w3,
                                                float* __restrict__ qo,
                                                float* __restrict__ ko,
                                                u16* __restrict__ vo)
{
  __shared__ u16 lAh[128 * LSTR];
  __shared__ u16 lBh[128 * LSTR];
  __shared__ u16 lAl[128 * LSTR];
  __shared__ u16 lBl[128 * LSTR];
  int z = blockIdx.z;
  const float* W = (z == 0) ? w1 : ((z == 1) ? w2 : w3);
  int t = threadIdx.x;
  int lane = t & 63, wv = t >> 6;
  int ln15 = lane & 15, q = lane >> 4;
  int pix0 = blockIdx.x * 128;
  int o0 = blockIdx.y * 128;
  int pw = (wv >> 1) * 64, ow = (wv & 1) * 64;
  f32x4 acc[4][4];
  #pragma unroll
  for (int i = 0; i < 4; ++i)
    #pragma unroll
    for (int j = 0; j < 4; ++j)
      acc[i][j] = (f32x4){0.f, 0.f, 0.f, 0.f};

  int srow = t >> 1;
  int sseg = (t & 1) * 16;
  const u16* gAh = XTh + (pix0 + srow) * 256 + sseg;
  const u16* gAl = XTl + (pix0 + srow) * 256 + sseg;
  const float* gB = W + (o0 + srow) * 256 + sseg;
  u16* sAh = lAh + srow * LSTR + sseg;
  u16* sAl = lAl + srow * LSTR + sseg;
  u16* sBh = lBh + srow * LSTR + sseg;
  u16* sBl = lBl + srow * LSTR + sseg;

  for (int kc = 0; kc < 256; kc += 32) {
    uint4 ah0 = *(const uint4*)(gAh + kc);
    uint4 ah1 = *(const uint4*)(gAh + kc + 8);
    uint4 al0 = make_uint4(0, 0, 0, 0), al1 = make_uint4(0, 0, 0, 0);
    if (z < 2) {
      al0 = *(const uint4*)(gAl + kc);
      al1 = *(const uint4*)(gAl + kc + 8);
    }
    float fv[16];
    *(float4*)(fv)      = ((const float4*)(gB + kc))[0];
    *(float4*)(fv + 4)  = ((const float4*)(gB + kc))[1];
    *(float4*)(fv + 8)  = ((const float4*)(gB + kc))[2];
    *(float4*)(fv + 12) = ((const float4*)(gB + kc))[3];
    u32 pbh[8], pbl[8];
    #pragma unroll
    for (int e = 0; e < 8; ++e) {
      float v0 = fv[2 * e], v1 = fv[2 * e + 1];
      u16 h0 = f2bf(v0), h1 = f2bf(v1);
      u16 l0 = f2bf(v0 - bf2f(h0)), l1 = f2bf(v1 - bf2f(h1));
      pbh[e] = (u32)h0 | ((u32)h1 << 16);
      pbl[e] = (u32)l0 | ((u32)l1 << 16);
    }
    __syncthreads();
    *(uint4*)sAh = ah0; *(uint4*)(sAh + 8) = ah1;
    *(uint4*)sBh = make_uint4(pbh[0], pbh[1], pbh[2], pbh[3]);
    *(uint4*)(sBh + 8) = make_uint4(pbh[4], pbh[5], pbh[6], pbh[7]);
    if (z < 2) {
      *(uint4*)sAl = al0; *(uint4*)(sAl + 8) = al1;
      *(uint4*)sBl = make_uint4(pbl[0], pbl[1], pbl[2], pbl[3]);
      *(uint4*)(sBl + 8) = make_uint4(pbl[4], pbl[5], pbl[6], pbl[7]);
    }
    __syncthreads();
    short8 afh[4], bfh[4];
    #pragma unroll
    for (int i = 0; i < 4; ++i)
      afh[i] = *(const short8*)(lAh + (pw + i * 16 + ln15) * LSTR + q * 8);
    #pragma unroll
    for (int j = 0; j < 4; ++j)
      bfh[j] = *(const short8*)(lBh + (ow + j * 16 + ln15) * LSTR + q * 8);
    #pragma unroll
    for (int i = 0; i < 4; ++i)
      #pragma unroll
      for (int j = 0; j < 4; ++j)
        acc[i][j] = __builtin_amdgcn_mfma_f32_16x16x32_bf16(afh[i], bfh[j], acc[i][j], 0, 0, 0);
    if (z < 2) {
      short8 afl[4], bfl[4];
      #pragma unroll
      for (int i = 0; i < 4; ++i)
        afl[i] = *(const short8*)(lAl + (pw + i * 16 + ln15) * LSTR + q * 8);
      #pragma unroll
      for (int j = 0; j < 4; ++j)
        bfl[j] = *(const short8*)(lBl + (ow + j * 16 + ln15) * LSTR + q * 8);
      #pragma unroll
      for (int i = 0; i < 4; ++i)
        #pragma unroll
        for (int j = 0; j < 4; ++j) {
          acc[i][j] = __builtin_amdgcn_mfma_f32_16x16x32_bf16(afh[i], bfl[j], acc[i][j], 0, 0, 0);
          acc[i][j] = __builtin_amdgcn_mfma_f32_16x16x32_bf16(afl[i], bfh[j], acc[i][j], 0, 0, 0);
        }
    }
  }

  // D: m(pixel) = pw + i*16 + q*4 + r, n(o) = ow + j*16 + ln15.
  // Store c-major: dst[o*16384 + pix]; the 4 acc regs are 4 consecutive pixels -> vector store.
  #pragma unroll
  for (int i = 0; i < 4; ++i) {
    int pixb = pix0 + pw + i * 16 + q * 4;
    #pragma unroll
    for (int j = 0; j < 4; ++j) {
      int o = o0 + ow + j * 16 + ln15;
      if (z == 2) {
        u32 p0 = (u32)f2bf(acc[i][j][0]) | ((u32)f2bf(acc[i][j][1]) << 16);
        u32 p1 = (u32)f2bf(acc[i][j][2]) | ((u32)f2bf(acc[i][j][3]) << 16);
        uint2 pv; pv.x = p0; pv.y = p1;
        *(uint2*)(vo + o * 16384 + pixb) = pv;
      } else {
        float* d = ((z == 0) ? qo : ko) + o * 16384 + pixb;
        *(float4*)d = make_float4(acc[i][j][0], acc[i][j][1], acc[i][j][2], acc[i][j][3]);
      }
    }
  }
}

// ------- Kernel 2: fused local attention. Half-row blocks, c-major in/out, LDS halo staging. -------
// grid (2, 256): blockIdx.y = row (b*64+h), blockIdx.x = half (32 pixels).
// lane: wp = lane&31 (pixel), cs = lane>>5. Wave wv. c-quad cqL = wv*8+cs*4+qi (per 128-c chunk cc).
__global__ __launch_bounds__(256, 2) void attn(const float* __restrict__ qo,
                                               const float* __restrict__ ko,
                                               const u16* __restrict__ vo,
                                               float* __restrict__ out)
{
  __shared__ float lq[256 * 33];     // q[c][wp], stride 33 (conflict-free); reused for out-transpose
  __shared__ float lk[32 * 41 * 4];  // [cq][slot(41-stride)][4c] quad-interleaved; slots 0..39 used
  __shared__ float lg[49 * 32];      // logits -> softmax weights [delta][wp]

  const int t = threadIdx.x;
  const int lane = t & 63, wv = t >> 6;
  const int wp = lane & 31, cs = lane >> 5;
  const int half = blockIdx.x, row = blockIdx.y;
  const int b = row >> 6, h = row & 63;
  const int rowbase = row * 64;           // == b*4096 + h*64
  const int w0 = half * 32 - 4;           // slot 0 <-> global w = w0 (zero-padded halo)

  // ---- stage q (thread t = channel t) ----
  {
    const float* src = qo + t * 16384 + rowbase + half * 32;
    float4 v[8];
    #pragma unroll
    for (int i = 0; i < 8; ++i) v[i] = ((const float4*)src)[i];
    #pragma unroll
    for (int i = 0; i < 8; ++i) {
      lq[t * 33 + i * 4 + 0] = v[i].x;
      lq[t * 33 + i * 4 + 1] = v[i].y;
      lq[t * 33 + i * 4 + 2] = v[i].z;
      lq[t * 33 + i * 4 + 3] = v[i].w;
    }
  }
  for (int i = t; i < 49 * 32; i += 256) lg[i] = 0.f;
  __syncthreads();

  float qreg[32];
  #pragma unroll
  for (int cc = 0; cc < 2; ++cc)
    #pragma unroll
    for (int qi = 0; qi < 4; ++qi)
      #pragma unroll
      for (int e = 0; e < 4; ++e)
        qreg[cc * 16 + qi * 4 + e] = lq[(cc * 128 + (wv * 8 + cs * 4 + qi) * 4 + e) * 33 + wp];

  const int cq1 = wv * 8 + (t & 7), sb1 = (t >> 3) & 7;  // staging pass1 ids (slots 0..31)
  const int cq2 = t >> 1,           sb2 = 8 + (t & 1);   // staging pass2 ids (t<64, slots 32..39)
  const int wq1 = w0 + sb1 * 4;
  const int wq2 = w0 + sb2 * 4;
  const bool cok1 = (wq1 >= 0) && (wq1 <= 60);
  const bool cok2 = (wq2 >= 0) && (wq2 <= 60);

  // ---- logits ----
  #pragma unroll
  for (int cc = 0; cc < 2; ++cc) {
    for (int dh = 0; dh < 7; ++dh) {
      const int krow = h + dh - 3;
      const bool rowok = (krow >= 0) && (krow < 64);
      const int gpix = rowbase + (dh - 3) * 64;
      __syncthreads();   // WAR: previous stage's reads done
      {
        const bool ok = rowok && cok1;
        const float* g = ko + (cc * 128 + cq1 * 4) * 16384 + gpix + wq1;
        float rr[4][4];
        #pragma unroll
        for (int e = 0; e < 4; ++e) {
          float4 vv = ok ? *(const float4*)(g + e * 16384) : make_float4(0.f, 0.f, 0.f, 0.f);
          rr[e][0] = vv.x; rr[e][1] = vv.y; rr[e][2] = vv.z; rr[e][3] = vv.w;
        }
        float* ld = lk + cq1 * 164 + sb1 * 16;
        #pragma unroll
        for (int i = 0; i < 4; ++i)
          ((float4*)ld)[i] = make_float4(rr[0][i], rr[1][i], rr[2][i], rr[3][i]);
      }
      if (t < 64) {
        const bool ok = rowok && cok2;
        const float* g = ko + (cc * 128 + cq2 * 4) * 16384 + gpix + wq2;
        float rr[4][4];
        #pragma unroll
        for (int e = 0; e < 4; ++e) {
          float4 vv = ok ? *(const float4*)(g + e * 16384) : make_float4(0.f, 0.f, 0.f, 0.f);
          rr[e][0] = vv.x; rr[e][1] = vv.y; rr[e][2] = vv.z; rr[e][3] = vv.w;
        }
        float* ld = lk + cq2 * 164 + sb2 * 16;
        #pragma unroll
        for (int i = 0; i < 4; ++i)
          ((float4*)ld)[i] = make_float4(rr[0][i], rr[1][i], rr[2][i], rr[3][i]);
      }
      __syncthreads();
      float a0 = 0.f, a1 = 0.f, a2 = 0.f, a3 = 0.f, a4 = 0.f, a5 = 0.f, a6 = 0.f;
      const float* bp = lk + (wp + 1) * 4;
      #pragma unroll
      for (int qi = 0; qi < 4; ++qi) {
        const int co = (wv * 8 + cs * 4 + qi) * 164;
        const float s0 = qreg[cc * 16 + qi * 4 + 0];
        const float s1 = qreg[cc * 16 + qi * 4 + 1];
        const float s2 = qreg[cc * 16 + qi * 4 + 2];
        const float s3 = qreg[cc * 16 + qi * 4 + 3];
        #pragma unroll
        for (int dw = 0; dw < 7; ++dw) {
          float4 kq = *(const float4*)(bp + co + dw * 4);
          float pr = s0 * kq.x + s1 * kq.y + s2 * kq.z + s3 * kq.w;
          if (dw == 0) a0 += pr; else if (dw == 1) a1 += pr; else if (dw == 2) a2 += pr;
          else if (dw == 3) a3 += pr; else if (dw == 4) a4 += pr; else if (dw == 5) a5 += pr;
          else a6 += pr;
        }
      }
      atomicAdd(&lg[(dh * 7 + 0) * 32 + wp], a0);
      atomicAdd(&lg[(dh * 7 + 1) * 32 + wp], a1);
      atomicAdd(&lg[(dh * 7 + 2) * 32 + wp], a2);
      atomicAdd(&lg[(dh * 7 + 3) * 32 + wp], a3);
      atomicAdd(&lg[(dh * 7 + 4) * 32 + wp], a4);
      atomicAdd(&lg[(dh * 7 + 5) * 32 + wp], a5);
      atomicAdd(&lg[(dh * 7 + 6) * 32 + wp], a6);
    }
  }
  __syncthreads();

  // ---- softmax over 49 (wave 0; cs groups duplicate harmlessly) ----
  if (wv == 0) {
    float ee[49];
    #pragma unroll
    for (int k = 0; k < 49; ++k) ee[k] = lg[k * 32 + wp];
    float m = ee[0];
    #pragma unroll
    for (int k = 1; k < 49; ++k) m = fmaxf(m, ee[k]);
    float s = 0.f;
    #pragma unroll
    for (int k = 0; k < 49; ++k) { ee[k] = __expf(ee[k] - m); s += ee[k]; }
    const float inv = 1.f / s;
    #pragma unroll
    for (int k = 0; k < 49; ++k) lg[k * 32 + wp] = ee[k] * inv;
  }
  __syncthreads();

  // ---- weighting ----
  float oacc[32];
  #pragma unroll
  for (int i = 0; i < 32; ++i) oacc[i] = 0.f;

  #pragma unroll
  for (int cc = 0; cc < 2; ++cc) {
    for (int dh = 0; dh < 7; ++dh) {
      const int krow = h + dh - 3;
      const bool rowok = (krow >= 0) && (krow < 64);
      const int gpix = rowbase + (dh - 3) * 64;
      __syncthreads();
      {
        const bool ok = rowok && cok1;
        const u16* g = vo + (cc * 128 + cq1 * 4) * 16384 + gpix + wq1;
        float rr[4][4];
        #pragma unroll
        for (int e = 0; e < 4; ++e) {
          uint2 uv = ok ? *(const uint2*)(g + e * 16384) : make_uint2(0u, 0u);
          rr[e][0] = bl(uv.x); rr[e][1] = bh(uv.x); rr[e][2] = bl(uv.y); rr[e][3] = bh(uv.y);
        }
        float* ld = lk + cq1 * 164 + sb1 * 16;
        #pragma unroll
        for (int i = 0; i < 4; ++i)
          ((float4*)ld)[i] = make_float4(rr[0][i], rr[1][i], rr[2][i], rr[3][i]);
      }
      if (t < 64) {
        const bool ok = rowok && cok2;
        const u16* g = vo + (cc * 128 + cq2 * 4) * 16384 + gpix + wq2;
        float rr[4][4];
        #pragma unroll
        for (int e = 0; e < 4; ++e) {
          uint2 uv = ok ? *(const uint2*)(g + e * 16384) : make_uint2(0u, 0u);
          rr[e][0] = bl(uv.x); rr[e][1] = bh(uv.x); rr[e][2] = bl(uv.y); rr[e][3] = bh(uv.y);
        }
        float* ld = lk + cq2 * 164 + sb2 * 16;
        #pragma unroll
        for (int i = 0; i < 4; ++i)
          ((float4*)ld)[i] = make_float4(rr[0][i], rr[1][i], rr[2][i], rr[3][i]);
      }
      __syncthreads();
      float wt7[7];
      #pragma unroll
      for (int dw = 0; dw < 7; ++dw) wt7[dw] = lg[(dh * 7 + dw) * 32 + wp];
      const float* bp = lk + (wp + 1) * 4;
      #pragma unroll
      for (int qi = 0; qi < 4; ++qi) {
        const int co = (wv * 8 + cs * 4 + qi) * 164;
        #pragma unroll
        for (int dw = 0; dw < 7; ++dw) {
          float4 vq = *(const float4*)(bp + co + dw * 4);
          oacc[cc * 16 + qi * 4 + 0] += vq.x * wt7[dw];
          oacc[cc * 16 + qi * 4 + 1] += vq.y * wt7[dw];
          oacc[cc * 16 + qi * 4 + 2] += vq.z * wt7[dw];
          oacc[cc * 16 + qi * 4 + 3] += vq.w * wt7[dw];
        }
      }
    }
  }
  __syncthreads();   // lq reads (qreg fill) long done; safe to reuse as transpose buffer

  #pragma unroll
  for (int cc = 0; cc < 2; ++cc)
    #pragma unroll
    for (int qi = 0; qi < 4; ++qi)
      #pragma unroll
      for (int e = 0; e < 4; ++e)
        lq[(cc * 128 + (wv * 8 + cs * 4 + qi) * 4 + e) * 33 + wp] = oacc[cc * 16 + qi * 4 + e];
  __syncthreads();

  {
    float* dst = out + (b * 256 + t) * 4096 + h * 64 + half * 32;
    #pragma unroll
    for (int i = 0; i < 8; ++i)
      ((float4*)dst)[i] = make_float4(lq[t * 33 + i * 4 + 0], lq[t * 33 + i * 4 + 1],
                                      lq[t * 33 + i * 4 + 2], lq[t * 33 + i * 4 + 3]);
  }
}

extern "C" void kernel_launch(void* const* d_in, const int* in_sizes, int n_in,
                              void* d_out, int out_size, void* d_ws, size_t ws_size,
                              hipStream_t stream)
{
  const float* x  = (const float*)d_in[0];
  const float* w1 = (const float*)d_in[1];
  const float* w2 = (const float*)d_in[2];
  const float* w3 = (const float*)d_in[3];
  float* out = (float*)d_out;

  // x hi/lo bf16 split lives in d_out (16 MB); consumed by qkv_gemm, then d_out is
  // fully rewritten by attn (which runs strictly after gemm on the stream).
  u16* XTh = (u16*)d_out;
  u16* XTl = XTh + 4194304;

  char* ws = (char*)d_ws;
  float* qo = (float*)ws;                 // 16 MB fp32 [c][pix]
  float* ko = (float*)(ws + (16u << 20)); // 16 MB fp32 [c][pix]
  u16*  vo  = (u16*)(ws + (32u << 20));   //  8 MB bf16 [c][pix]

  split_in<<<dim3(64, 4, 4), 256, 0, stream>>>(x, XTh, XTl);
  qkv_gemm<<<dim3(128, 2, 3), 256, 0, stream>>>(XTh, XTl, w1, w2, w3, qo, ko, vo);
  attn<<<dim3(2, 256), 256, 0, stream>>>(qo, ko, vo, out);
}

// Round 4
// 193.505 us; speedup vs baseline: 2.9326x; 2.9326x over previous
//
#include <hip/hip_runtime.h>

typedef unsigned short u16;
typedef unsigned int u32;
typedef __attribute__((ext_vector_type(8))) short short8;
typedef __attribute__((ext_vector_type(4))) float f32x4;

__device__ __forceinline__ float bl(u32 u){ return __builtin_bit_cast(float, u << 16); }
__device__ __forceinline__ float bh(u32 u){ return __builtin_bit_cast(float, u & 0xffff0000u); }
__device__ __forceinline__ float bf2f(u16 h){ return __builtin_bit_cast(float, ((u32)h) << 16); }
__device__ __forceinline__ u16 f2bf(float f){
  u32 u = __builtin_bit_cast(u32, f);
  u32 r = u + 0x7fffu + ((u >> 16) & 1u);
  return (u16)(r >> 16);
}

// ------- Kernel 0: x fp32 [b][c][hw] -> XTh/XTl bf16 hi/lo split, pixel-major [pix][c] -------
__global__ __launch_bounds__(256) void split_in(const float* __restrict__ x,
                                                u16* __restrict__ XTh,
                                                u16* __restrict__ XTl)
{
  __shared__ float tile[64 * 68];
  int t = threadIdx.x;
  int hw0 = blockIdx.x * 64, c0 = blockIdx.y * 64, b = blockIdx.z;
  {
    int cl = t >> 2, seg = (t & 3) * 16;
    const float* src = x + (b * 256 + c0 + cl) * 4096 + hw0 + seg;
    float4 v0 = ((const float4*)src)[0];
    float4 v1 = ((const float4*)src)[1];
    float4 v2 = ((const float4*)src)[2];
    float4 v3 = ((const float4*)src)[3];
    float* d = tile + cl * 68 + seg;
    ((float4*)d)[0] = v0; ((float4*)d)[1] = v1;
    ((float4*)d)[2] = v2; ((float4*)d)[3] = v3;
  }
  __syncthreads();
  {
    int hwl = t >> 2, cs = (t & 3) * 16;
    u32 ph[8], pl[8];
    #pragma unroll
    for (int e = 0; e < 8; ++e) {
      float v0 = tile[(cs + 2 * e) * 68 + hwl];
      float v1 = tile[(cs + 2 * e + 1) * 68 + hwl];
      u16 h0 = f2bf(v0), h1 = f2bf(v1);
      u16 l0 = f2bf(v0 - bf2f(h0)), l1 = f2bf(v1 - bf2f(h1));
      ph[e] = (u32)h0 | ((u32)h1 << 16);
      pl[e] = (u32)l0 | ((u32)l1 << 16);
    }
    int off = (b * 4096 + hw0 + hwl) * 256 + c0 + cs;
    *(uint4*)(XTh + off)     = make_uint4(ph[0], ph[1], ph[2], ph[3]);
    *(uint4*)(XTh + off + 8) = make_uint4(ph[4], ph[5], ph[6], ph[7]);
    *(uint4*)(XTl + off)     = make_uint4(pl[0], pl[1], pl[2], pl[3]);
    *(uint4*)(XTl + off + 8) = make_uint4(pl[4], pl[5], pl[6], pl[7]);
  }
}

// ------- Kernel 0b: w1|w2|w3 fp32 [o][c] -> Wh/Wl bf16 hi/lo (concatenated, same layout) -------
__global__ __launch_bounds__(256) void wsplit(const float* __restrict__ w1,
                                              const float* __restrict__ w2,
                                              const float* __restrict__ w3,
                                              u16* __restrict__ Wh,
                                              u16* __restrict__ Wl)
{
  int i = (blockIdx.x * 256 + threadIdx.x) * 4;   // 0..196604, matrix = i>>16
  int z = i >> 16, off = i & 65535;
  const float* w = (z == 0) ? w1 : ((z == 1) ? w2 : w3);
  float4 v = *(const float4*)(w + off);
  u16 h0 = f2bf(v.x), h1 = f2bf(v.y), h2 = f2bf(v.z), h3 = f2bf(v.w);
  u16 l0 = f2bf(v.x - bf2f(h0)), l1 = f2bf(v.y - bf2f(h1));
  u16 l2 = f2bf(v.z - bf2f(h2)), l3 = f2bf(v.w - bf2f(h3));
  uint2 hv; hv.x = (u32)h0 | ((u32)h1 << 16); hv.y = (u32)h2 | ((u32)h3 << 16);
  uint2 lv; lv.x = (u32)l0 | ((u32)l1 << 16); lv.y = (u32)l2 | ((u32)l3 << 16);
  *(uint2*)(Wh + i) = hv;
  *(uint2*)(Wl + i) = lv;
}

// ------- Kernel 1: q/k via 3-pass split-bf16 MFMA, v via 1-pass bf16. Pre-split W (no repack). -------
// grid (128, 2, 3). z=0->q (fp32), z=1->k (fp32), z=2->v (bf16). Output pixel-major [pix][c].
#define LSTR 40
__global__ __launch_bounds__(256) void qkv_gemm(const u16* __restrict__ XTh,
                                                const u16* __restrict__ XTl,
                                                const u16* __restrict__ Wh,
                                                const u16* __restrict__ Wl,
                                                float* __restrict__ qo,
                                                float* __restrict__ ko,
                                                u16* __restrict__ vo)
{
  __shared__ u16 lAh[128 * LSTR];
  __shared__ u16 lBh[128 * LSTR];
  __shared__ u16 lAl[128 * LSTR];
  __shared__ u16 lBl[128 * LSTR];
  int z = blockIdx.z;
  int t = threadIdx.x;
  int lane = t & 63, wv = t >> 6;
  int ln15 = lane & 15, q = lane >> 4;
  int pix0 = blockIdx.x * 128;
  int o0 = blockIdx.y * 128;
  int pw = (wv >> 1) * 64, ow = (wv & 1) * 64;
  f32x4 acc[4][4];
  #pragma unroll
  for (int i = 0; i < 4; ++i)
    #pragma unroll
    for (int j = 0; j < 4; ++j)
      acc[i][j] = (f32x4){0.f, 0.f, 0.f, 0.f};

  int srow = t >> 1;
  int sseg = (t & 1) * 16;
  const u16* gAh = XTh + (pix0 + srow) * 256 + sseg;
  const u16* gAl = XTl + (pix0 + srow) * 256 + sseg;
  const u16* gBh = Wh + z * 65536 + (o0 + srow) * 256 + sseg;
  const u16* gBl = Wl + z * 65536 + (o0 + srow) * 256 + sseg;
  u16* sAh = lAh + srow * LSTR + sseg;
  u16* sAl = lAl + srow * LSTR + sseg;
  u16* sBh = lBh + srow * LSTR + sseg;
  u16* sBl = lBl + srow * LSTR + sseg;

  for (int kc = 0; kc < 256; kc += 32) {
    uint4 ah0 = *(const uint4*)(gAh + kc);
    uint4 ah1 = *(const uint4*)(gAh + kc + 8);
    uint4 bh0 = *(const uint4*)(gBh + kc);
    uint4 bh1 = *(const uint4*)(gBh + kc + 8);
    uint4 al0 = make_uint4(0,0,0,0), al1 = make_uint4(0,0,0,0);
    uint4 bl0 = make_uint4(0,0,0,0), bl1 = make_uint4(0,0,0,0);
    if (z < 2) {
      al0 = *(const uint4*)(gAl + kc);
      al1 = *(const uint4*)(gAl + kc + 8);
      bl0 = *(const uint4*)(gBl + kc);
      bl1 = *(const uint4*)(gBl + kc + 8);
    }
    __syncthreads();                      // WAR: previous iter's frag reads done
    *(uint4*)sAh = ah0; *(uint4*)(sAh + 8) = ah1;
    *(uint4*)sBh = bh0; *(uint4*)(sBh + 8) = bh1;
    if (z < 2) {
      *(uint4*)sAl = al0; *(uint4*)(sAl + 8) = al1;
      *(uint4*)sBl = bl0; *(uint4*)(sBl + 8) = bl1;
    }
    __syncthreads();
    short8 afh[4], bfh[4];
    #pragma unroll
    for (int i = 0; i < 4; ++i)
      afh[i] = *(const short8*)(lAh + (pw + i * 16 + ln15) * LSTR + q * 8);
    #pragma unroll
    for (int j = 0; j < 4; ++j)
      bfh[j] = *(const short8*)(lBh + (ow + j * 16 + ln15) * LSTR + q * 8);
    #pragma unroll
    for (int i = 0; i < 4; ++i)
      #pragma unroll
      for (int j = 0; j < 4; ++j)
        acc[i][j] = __builtin_amdgcn_mfma_f32_16x16x32_bf16(afh[i], bfh[j], acc[i][j], 0, 0, 0);
    if (z < 2) {
      short8 afl[4], bfl[4];
      #pragma unroll
      for (int i = 0; i < 4; ++i)
        afl[i] = *(const short8*)(lAl + (pw + i * 16 + ln15) * LSTR + q * 8);
      #pragma unroll
      for (int j = 0; j < 4; ++j)
        bfl[j] = *(const short8*)(lBl + (ow + j * 16 + ln15) * LSTR + q * 8);
      #pragma unroll
      for (int i = 0; i < 4; ++i)
        #pragma unroll
        for (int j = 0; j < 4; ++j) {
          acc[i][j] = __builtin_amdgcn_mfma_f32_16x16x32_bf16(afh[i], bfl[j], acc[i][j], 0, 0, 0);
          acc[i][j] = __builtin_amdgcn_mfma_f32_16x16x32_bf16(afl[i], bfh[j], acc[i][j], 0, 0, 0);
        }
    }
  }

  // D layout: m(pixel) = pw + i*16 + q*4 + r, n(o) = ow + j*16 + ln15
  #pragma unroll
  for (int i = 0; i < 4; ++i) {
    #pragma unroll
    for (int r = 0; r < 4; ++r) {
      int pix = pix0 + pw + i * 16 + q * 4 + r;
      int ob = o0 + ow + ln15;
      if (z == 2) {
        u16* d = vo + pix * 256 + ob;
        #pragma unroll
        for (int j = 0; j < 4; ++j) d[j * 16] = f2bf(acc[i][j][r]);
      } else {
        float* d = ((z == 0) ? qo : ko) + pix * 256 + ob;
        #pragma unroll
        for (int j = 0; j < 4; ++j) d[j * 16] = acc[i][j][r];
      }
    }
  }
}

// ------- Kernel 2: local attention, one wave per pixel. q/k fp32, v bf16, out fp32 -------
// outt aliases x1t (q): wave p reads q[p] strictly before writing outt[p].
__global__ __launch_bounds__(256) void attn(const float* x1t,
                                            const float* __restrict__ x2t,
                                            const u16* __restrict__ x3t,
                                            float* outt)
{
  __shared__ float lg[4][52];
  __shared__ float wsm[4][52];
  int t = threadIdx.x;
  int wv = t >> 6, lane = t & 63;
  int p = blockIdx.x * 4 + wv;
  int b = p >> 12, hw = p & 4095;
  int h = hw >> 6, w = hw & 63;
  int cg = lane & 15, kk = lane >> 4;
  int pbase = b << 12;

  const float* qp = x1t + p * 256 + cg * 16;
  float4 q0 = *(const float4*)qp;
  float4 q1 = *(const float4*)(qp + 4);
  float4 q2 = *(const float4*)(qp + 8);
  float4 q3 = *(const float4*)(qp + 12);

  for (int kb = 0; kb < 52; kb += 4) {
    int k = kb + kk;
    float partial = 0.f;
    if (k < 49) {
      int dh = k / 7, dw = k % 7;
      int nh = h + dh - 3, nw = w + dw - 3;
      if ((u32)nh < 64u && (u32)nw < 64u) {
        const float* kp = x2t + (pbase + (nh << 6) + nw) * 256 + cg * 16;
        float4 k0 = *(const float4*)kp;
        float4 k1 = *(const float4*)(kp + 4);
        float4 k2 = *(const float4*)(kp + 8);
        float4 k3 = *(const float4*)(kp + 12);
        partial = q0.x * k0.x + q0.y * k0.y + q0.z * k0.z + q0.w * k0.w
                + q1.x * k1.x + q1.y * k1.y + q1.z * k1.z + q1.w * k1.w
                + q2.x * k2.x + q2.y * k2.y + q2.z * k2.z + q2.w * k2.w
                + q3.x * k3.x + q3.y * k3.y + q3.z * k3.z + q3.w * k3.w;
      }
    }
    partial += __shfl_xor(partial, 1);
    partial += __shfl_xor(partial, 2);
    partial += __shfl_xor(partial, 4);
    partial += __shfl_xor(partial, 8);
    if (cg == 0 && k < 49) lg[wv][k] = partial;
  }
  __syncthreads();

  float lv = (lane < 49) ? lg[wv][lane] : -3.0e38f;
  float m = lv;
  #pragma unroll
  for (int msk = 1; msk < 64; msk <<= 1) m = fmaxf(m, __shfl_xor(m, msk));
  float e = (lane < 49) ? __expf(lv - m) : 0.f;
  float s = e;
  #pragma unroll
  for (int msk = 1; msk < 64; msk <<= 1) s += __shfl_xor(s, msk);
  if (lane < 49) wsm[wv][lane] = e / s;
  __syncthreads();

  float a0 = 0.f, a1 = 0.f, a2 = 0.f, a3 = 0.f;
  int c0 = lane * 4;
  for (int dh = 0; dh < 7; ++dh) {
    int nh = h + dh - 3;
    if ((u32)nh >= 64u) continue;
    #pragma unroll
    for (int dw = 0; dw < 7; ++dw) {
      int nw = w + dw - 3;
      if ((u32)nw >= 64u) continue;
      float wk = wsm[wv][dh * 7 + dw];
      const u16* vp = x3t + (pbase + (nh << 6) + nw) * 256 + c0;
      uint2 vv = *(const uint2*)vp;
      a0 += wk * bl(vv.x); a1 += wk * bh(vv.x);
      a2 += wk * bl(vv.y); a3 += wk * bh(vv.y);
    }
  }
  *(float4*)(outt + p * 256 + c0) = make_float4(a0, a1, a2, a3);
}

// ------- Kernel 3: outt fp32 [pix][c] -> out fp32 [b][c][hw] -------
__global__ __launch_bounds__(256) void transpose_out(const float* __restrict__ outt,
                                                     float* __restrict__ out)
{
  __shared__ float tile[64 * 68];
  int t = threadIdx.x;
  int hw0 = blockIdx.x * 64, c0 = blockIdx.y * 64, b = blockIdx.z;
  {
    int pl = t >> 2, seg = (t & 3) * 16;
    const float* src = outt + (b * 4096 + hw0 + pl) * 256 + c0 + seg;
    float4 v0 = ((const float4*)src)[0];
    float4 v1 = ((const float4*)src)[1];
    float4 v2 = ((const float4*)src)[2];
    float4 v3 = ((const float4*)src)[3];
    float* d = tile + pl * 68 + seg;
    ((float4*)d)[0] = v0; ((float4*)d)[1] = v1;
    ((float4*)d)[2] = v2; ((float4*)d)[3] = v3;
  }
  __syncthreads();
  {
    int cl = t >> 2, hs = (t & 3) * 16;
    float vv[16];
    #pragma unroll
    for (int e = 0; e < 16; ++e) vv[e] = tile[(hs + e) * 68 + cl];
    float* dst = out + (b * 256 + c0 + cl) * 4096 + hw0 + hs;
    ((float4*)dst)[0] = make_float4(vv[0], vv[1], vv[2], vv[3]);
    ((float4*)dst)[1] = make_float4(vv[4], vv[5], vv[6], vv[7]);
    ((float4*)dst)[2] = make_float4(vv[8], vv[9], vv[10], vv[11]);
    ((float4*)dst)[3] = make_float4(vv[12], vv[13], vv[14], vv[15]);
  }
}

extern "C" void kernel_launch(void* const* d_in, const int* in_sizes, int n_in,
                              void* d_out, int out_size, void* d_ws, size_t ws_size,
                              hipStream_t stream)
{
  const float* x  = (const float*)d_in[0];
  const float* w1 = (const float*)d_in[1];
  const float* w2 = (const float*)d_in[2];
  const float* w3 = (const float*)d_in[3];
  float* out = (float*)d_out;

  // x hi/lo bf16 split lives in d_out (16 MB); consumed by qkv_gemm, then d_out is
  // fully rewritten by transpose_out at the end.
  u16* XTh = (u16*)d_out;
  u16* XTl = XTh + 4194304;

  char* ws = (char*)d_ws;
  float* qo = (float*)ws;                 // 16 MB fp32 [pix][c] (query)
  float* ko = (float*)(ws + (16u << 20)); // 16 MB fp32 [pix][c] (key)
  u16*  vo  = (u16*)(ws + (32u << 20));   //  8 MB bf16 [pix][c] (value)
  u16*  Wh  = (u16*)(ws + (40u << 20));   // 384 KB bf16 hi of w1|w2|w3
  u16*  Wl  = Wh + 196608;                // 384 KB bf16 lo
  float* outt = qo;                       // attn output aliases q (safe, see attn)

  split_in<<<dim3(64, 4, 4), 256, 0, stream>>>(x, XTh, XTl);
  wsplit<<<192, 256, 0, stream>>>(w1, w2, w3, Wh, Wl);
  qkv_gemm<<<dim3(128, 2, 3), 256, 0, stream>>>(XTh, XTl, Wh, Wl, qo, ko, vo);
  attn<<<4096, 256, 0, stream>>>(qo, ko, vo, outt);
  transpose_out<<<dim3(64, 4, 4), 256, 0, stream>>>(outt, out);
}

// Round 5
// 153.748 us; speedup vs baseline: 3.6910x; 1.2586x over previous
//
#include <hip/hip_runtime.h>

typedef unsigned short u16;
typedef unsigned int u32;
typedef __attribute__((ext_vector_type(8))) short short8;
typedef __attribute__((ext_vector_type(4))) float f32x4;

__device__ __forceinline__ float bl(u32 u){ return __builtin_bit_cast(float, u << 16); }
__device__ __forceinline__ float bh(u32 u){ return __builtin_bit_cast(float, u & 0xffff0000u); }
__device__ __forceinline__ float bf2f(u16 h){ return __builtin_bit_cast(float, ((u32)h) << 16); }
__device__ __forceinline__ u16 f2bf(float f){
  u32 u = __builtin_bit_cast(u32, f);
  u32 r = u + 0x7fffu + ((u >> 16) & 1u);
  return (u16)(r >> 16);
}

// ------- Kernel 0: x fp32 [b][c][hw] -> XTh/XTl bf16 hi/lo split, pixel-major [pix][c] -------
__global__ __launch_bounds__(256) void split_in(const float* __restrict__ x,
                                                u16* __restrict__ XTh,
                                                u16* __restrict__ XTl)
{
  __shared__ float tile[64 * 68];
  int t = threadIdx.x;
  int hw0 = blockIdx.x * 64, c0 = blockIdx.y * 64, b = blockIdx.z;
  {
    int cl = t >> 2, seg = (t & 3) * 16;
    const float* src = x + (b * 256 + c0 + cl) * 4096 + hw0 + seg;
    float4 v0 = ((const float4*)src)[0];
    float4 v1 = ((const float4*)src)[1];
    float4 v2 = ((const float4*)src)[2];
    float4 v3 = ((const float4*)src)[3];
    float* d = tile + cl * 68 + seg;
    ((float4*)d)[0] = v0; ((float4*)d)[1] = v1;
    ((float4*)d)[2] = v2; ((float4*)d)[3] = v3;
  }
  __syncthreads();
  {
    int hwl = t >> 2, cs = (t & 3) * 16;
    u32 ph[8], pl[8];
    #pragma unroll
    for (int e = 0; e < 8; ++e) {
      float v0 = tile[(cs + 2 * e) * 68 + hwl];
      float v1 = tile[(cs + 2 * e + 1) * 68 + hwl];
      u16 h0 = f2bf(v0), h1 = f2bf(v1);
      u16 l0 = f2bf(v0 - bf2f(h0)), l1 = f2bf(v1 - bf2f(h1));
      ph[e] = (u32)h0 | ((u32)h1 << 16);
      pl[e] = (u32)l0 | ((u32)l1 << 16);
    }
    int off = (b * 4096 + hw0 + hwl) * 256 + c0 + cs;
    *(uint4*)(XTh + off)     = make_uint4(ph[0], ph[1], ph[2], ph[3]);
    *(uint4*)(XTh + off + 8) = make_uint4(ph[4], ph[5], ph[6], ph[7]);
    *(uint4*)(XTl + off)     = make_uint4(pl[0], pl[1], pl[2], pl[3]);
    *(uint4*)(XTl + off + 8) = make_uint4(pl[4], pl[5], pl[6], pl[7]);
  }
}

// ------- Kernel 0b: w1|w2|w3 fp32 [o][c] -> Wh/Wl bf16 hi/lo -------
__global__ __launch_bounds__(256) void wsplit(const float* __restrict__ w1,
                                              const float* __restrict__ w2,
                                              const float* __restrict__ w3,
                                              u16* __restrict__ Wh,
                                              u16* __restrict__ Wl)
{
  int i = (blockIdx.x * 256 + threadIdx.x) * 4;
  int z = i >> 16, off = i & 65535;
  const float* w = (z == 0) ? w1 : ((z == 1) ? w2 : w3);
  float4 v = *(const float4*)(w + off);
  u16 h0 = f2bf(v.x), h1 = f2bf(v.y), h2 = f2bf(v.z), h3 = f2bf(v.w);
  u16 l0 = f2bf(v.x - bf2f(h0)), l1 = f2bf(v.y - bf2f(h1));
  u16 l2 = f2bf(v.z - bf2f(h2)), l3 = f2bf(v.w - bf2f(h3));
  uint2 hv; hv.x = (u32)h0 | ((u32)h1 << 16); hv.y = (u32)h2 | ((u32)h3 << 16);
  uint2 lv; lv.x = (u32)l0 | ((u32)l1 << 16); lv.y = (u32)l2 | ((u32)l3 << 16);
  *(uint2*)(Wh + i) = hv;
  *(uint2*)(Wl + i) = lv;
}

// ------- Kernel 1: q/k via 3-pass split-bf16 MFMA -> hi/lo bf16 pixel-major;
//         v via 1-pass -> bf16 c-major. grid (128, 2, 3). -------
#define LSTR 40
__global__ __launch_bounds__(256) void qkv_gemm(const u16* __restrict__ XTh,
                                                const u16* __restrict__ XTl,
                                                const u16* __restrict__ Wh,
                                                const u16* __restrict__ Wl,
                                                u16* __restrict__ qh_, u16* __restrict__ ql_,
                                                u16* __restrict__ kh_, u16* __restrict__ kl_,
                                                u16* __restrict__ vo)
{
  __shared__ u16 lAh[128 * LSTR];
  __shared__ u16 lBh[128 * LSTR];
  __shared__ u16 lAl[128 * LSTR];
  __shared__ u16 lBl[128 * LSTR];
  int z = blockIdx.z;
  int t = threadIdx.x;
  int lane = t & 63, wv = t >> 6;
  int ln15 = lane & 15, q = lane >> 4;
  int pix0 = blockIdx.x * 128;
  int o0 = blockIdx.y * 128;
  int pw = (wv >> 1) * 64, ow = (wv & 1) * 64;
  f32x4 acc[4][4];
  #pragma unroll
  for (int i = 0; i < 4; ++i)
    #pragma unroll
    for (int j = 0; j < 4; ++j)
      acc[i][j] = (f32x4){0.f, 0.f, 0.f, 0.f};

  int srow = t >> 1;
  int sseg = (t & 1) * 16;
  const u16* gAh = XTh + (pix0 + srow) * 256 + sseg;
  const u16* gAl = XTl + (pix0 + srow) * 256 + sseg;
  const u16* gBh = Wh + z * 65536 + (o0 + srow) * 256 + sseg;
  const u16* gBl = Wl + z * 65536 + (o0 + srow) * 256 + sseg;
  u16* sAh = lAh + srow * LSTR + sseg;
  u16* sAl = lAl + srow * LSTR + sseg;
  u16* sBh = lBh + srow * LSTR + sseg;
  u16* sBl = lBl + srow * LSTR + sseg;

  for (int kc = 0; kc < 256; kc += 32) {
    uint4 ah0 = *(const uint4*)(gAh + kc);
    uint4 ah1 = *(const uint4*)(gAh + kc + 8);
    uint4 bh0 = *(const uint4*)(gBh + kc);
    uint4 bh1 = *(const uint4*)(gBh + kc + 8);
    uint4 al0 = make_uint4(0,0,0,0), al1 = make_uint4(0,0,0,0);
    uint4 bl0 = make_uint4(0,0,0,0), bl1 = make_uint4(0,0,0,0);
    if (z < 2) {
      al0 = *(const uint4*)(gAl + kc);
      al1 = *(const uint4*)(gAl + kc + 8);
      bl0 = *(const uint4*)(gBl + kc);
      bl1 = *(const uint4*)(gBl + kc + 8);
    }
    __syncthreads();
    *(uint4*)sAh = ah0; *(uint4*)(sAh + 8) = ah1;
    *(uint4*)sBh = bh0; *(uint4*)(sBh + 8) = bh1;
    if (z < 2) {
      *(uint4*)sAl = al0; *(uint4*)(sAl + 8) = al1;
      *(uint4*)sBl = bl0; *(uint4*)(sBl + 8) = bl1;
    }
    __syncthreads();
    short8 afh[4], bfh[4];
    #pragma unroll
    for (int i = 0; i < 4; ++i)
      afh[i] = *(const short8*)(lAh + (pw + i * 16 + ln15) * LSTR + q * 8);
    #pragma unroll
    for (int j = 0; j < 4; ++j)
      bfh[j] = *(const short8*)(lBh + (ow + j * 16 + ln15) * LSTR + q * 8);
    #pragma unroll
    for (int i = 0; i < 4; ++i)
      #pragma unroll
      for (int j = 0; j < 4; ++j)
        acc[i][j] = __builtin_amdgcn_mfma_f32_16x16x32_bf16(afh[i], bfh[j], acc[i][j], 0, 0, 0);
    if (z < 2) {
      short8 afl[4], bfl[4];
      #pragma unroll
      for (int i = 0; i < 4; ++i)
        afl[i] = *(const short8*)(lAl + (pw + i * 16 + ln15) * LSTR + q * 8);
      #pragma unroll
      for (int j = 0; j < 4; ++j)
        bfl[j] = *(const short8*)(lBl + (ow + j * 16 + ln15) * LSTR + q * 8);
      #pragma unroll
      for (int i = 0; i < 4; ++i)
        #pragma unroll
        for (int j = 0; j < 4; ++j) {
          acc[i][j] = __builtin_amdgcn_mfma_f32_16x16x32_bf16(afh[i], bfl[j], acc[i][j], 0, 0, 0);
          acc[i][j] = __builtin_amdgcn_mfma_f32_16x16x32_bf16(afl[i], bfh[j], acc[i][j], 0, 0, 0);
        }
    }
  }

  // D: m(pixel) = pw + i*16 + q*4 + r, n(o) = ow + j*16 + ln15
  if (z == 2) {
    // v: c-major [o][pix]; 4 acc regs = 4 consecutive pixels -> packed uint2 store
    #pragma unroll
    for (int i = 0; i < 4; ++i) {
      int pixb = pix0 + pw + i * 16 + q * 4;
      #pragma unroll
      for (int j = 0; j < 4; ++j) {
        int o = o0 + ow + j * 16 + ln15;
        u32 p0 = (u32)f2bf(acc[i][j][0]) | ((u32)f2bf(acc[i][j][1]) << 16);
        u32 p1 = (u32)f2bf(acc[i][j][2]) | ((u32)f2bf(acc[i][j][3]) << 16);
        uint2 pv; pv.x = p0; pv.y = p1;
        *(uint2*)(vo + o * 16384 + pixb) = pv;
      }
    }
  } else {
    u16* dsth = (z == 0) ? qh_ : kh_;
    u16* dstl = (z == 0) ? ql_ : kl_;
    #pragma unroll
    for (int i = 0; i < 4; ++i) {
      #pragma unroll
      for (int r = 0; r < 4; ++r) {
        int pix = pix0 + pw + i * 16 + q * 4 + r;
        int ob = o0 + ow + ln15;
        #pragma unroll
        for (int j = 0; j < 4; ++j) {
          float vv = acc[i][j][r];
          u16 hh = f2bf(vv);
          u16 ll = f2bf(vv - bf2f(hh));
          dsth[pix * 256 + ob + j * 16] = hh;
          dstl[pix * 256 + ob + j * 16] = ll;
        }
      }
    }
  }
}

// ------- Kernel 2: banded-MFMA local attention. Block = half image row (32 px). -------
// Phase 1: logits via 16x16x32 MFMA, 2 n-windows per m-tile, 3-pass hi/lo.
// Phase 2: out = V * P_band via 16x16x32 MFMA, writes d_out native [b][c][h][w].
__global__ __launch_bounds__(256, 2) void attn(const u16* __restrict__ qh_,
                                               const u16* __restrict__ ql_,
                                               const u16* __restrict__ kh_,
                                               const u16* __restrict__ kl_,
                                               const u16* __restrict__ vo,
                                               float* __restrict__ out)
{
  __shared__ float lg2[2][32][57];       // logits, split by cc-half (summed in softmax)
  __shared__ u16 pb[2][7][16][40];       // banded prob B-operand [mt][dh][m'][n'(pad 40)]

  const int t = threadIdx.x;
  const int lane = t & 63, wv = t >> 6;
  const int l15 = lane & 15, q4 = lane >> 4;
  const int half = blockIdx.x & 1;
  const int row = blockIdx.x >> 1;        // b*64 + h
  const int b = row >> 6, h = row & 63;

  for (int i = t; i < 2 * 32 * 57; i += 256) ((float*)lg2)[i] = 0.f;
  for (int i = t; i < 4480; i += 256) ((u32*)pb)[i] = 0u;
  __syncthreads();

  const short8 zf = {0, 0, 0, 0, 0, 0, 0, 0};

  // ---------- phase 1: logits ----------
  {
    const int mt = wv >> 1, ch = wv & 1;       // wave -> (m-tile, c-half)
    const int wbase = half * 32 + mt * 16;     // m-tile w start
    short8 qfh[4], qfl[4];
    {
      const int pix = row * 64 + wbase + l15;  // A: m = l15 (query pixel)
      const u16* qhp = qh_ + pix * 256;
      const u16* qlp = ql_ + pix * 256;
      #pragma unroll
      for (int u = 0; u < 4; ++u) {
        const int c0 = (ch * 4 + u) * 32 + q4 * 8;
        qfh[u] = *(const short8*)(qhp + c0);
        qfl[u] = *(const short8*)(qlp + c0);
      }
    }
    const int wn0 = wbase - 8 + l15;           // win0 neighbor w (B: n = l15)
    const int wn1 = wbase + 8 + l15;           // win1 neighbor w
    const bool ok0 = (wn0 >= 0) && (wn0 < 64);
    const bool ok1 = (wn1 >= 0) && (wn1 < 64);
    for (int dh = 0; dh < 7; ++dh) {
      const int rdh = h + dh - 3;
      if (rdh < 0 || rdh >= 64) continue;      // OOB row: logits stay 0 (pre-zeroed)
      const int rp = (row + dh - 3) * 64;
      const u16* k0h = kh_ + (rp + wn0) * 256;
      const u16* k0l = kl_ + (rp + wn0) * 256;
      const u16* k1h = kh_ + (rp + wn1) * 256;
      const u16* k1l = kl_ + (rp + wn1) * 256;
      f32x4 a0 = {0.f, 0.f, 0.f, 0.f}, a1 = {0.f, 0.f, 0.f, 0.f};
      #pragma unroll
      for (int u = 0; u < 4; ++u) {
        const int c0 = (ch * 4 + u) * 32 + q4 * 8;
        short8 b0h = ok0 ? *(const short8*)(k0h + c0) : zf;
        short8 b1h = ok1 ? *(const short8*)(k1h + c0) : zf;
        short8 b0l = ok0 ? *(const short8*)(k0l + c0) : zf;
        short8 b1l = ok1 ? *(const short8*)(k1l + c0) : zf;
        a0 = __builtin_amdgcn_mfma_f32_16x16x32_bf16(qfh[u], b0h, a0, 0, 0, 0);
        a1 = __builtin_amdgcn_mfma_f32_16x16x32_bf16(qfh[u], b1h, a1, 0, 0, 0);
        a0 = __builtin_amdgcn_mfma_f32_16x16x32_bf16(qfh[u], b0l, a0, 0, 0, 0);
        a1 = __builtin_amdgcn_mfma_f32_16x16x32_bf16(qfh[u], b1l, a1, 0, 0, 0);
        a0 = __builtin_amdgcn_mfma_f32_16x16x32_bf16(qfl[u], b0h, a0, 0, 0, 0);
        a1 = __builtin_amdgcn_mfma_f32_16x16x32_bf16(qfl[u], b1h, a1, 0, 0, 0);
      }
      // scatter band entries: D col n=l15, row m=q4*4+r; dw = n_w - m_w + 3
      #pragma unroll
      for (int r = 0; r < 4; ++r) {
        const int mloc = mt * 16 + q4 * 4 + r;
        const int dw0 = l15 - q4 * 4 - r - 5;
        const int dw1 = dw0 + 16;
        if (dw0 >= 0 && dw0 < 7) lg2[ch][mloc][dh * 7 + dw0] = a0[r];
        if (dw1 >= 0 && dw1 < 7) lg2[ch][mloc][dh * 7 + dw1] = a1[r];
      }
    }
  }
  __syncthreads();

  // ---------- softmax (t < 32: one thread per pixel) ----------
  if (t < 32) {
    const int m15 = t & 15, mtt = t >> 4;
    float mx = -3.0e38f;
    for (int i = 0; i < 49; ++i)
      mx = fmaxf(mx, lg2[0][t][i] + lg2[1][t][i]);
    float s = 0.f;
    for (int i = 0; i < 49; ++i)
      s += __expf(lg2[0][t][i] + lg2[1][t][i] - mx);
    const float inv = 1.f / s;
    #pragma unroll
    for (int dh = 0; dh < 7; ++dh)
      #pragma unroll
      for (int dw = 0; dw < 7; ++dw) {
        float l = lg2[0][t][dh * 7 + dw] + lg2[1][t][dh * 7 + dw];
        pb[mtt][dh][m15][m15 + 5 + dw] = f2bf(__expf(l - mx) * inv);
      }
  }
  __syncthreads();

  // ---------- phase 2: out[c][m'] = sum_n' v[c][n'] * P[m'][n'] ----------
  #pragma unroll
  for (int i = 0; i < 4; ++i) {
    const int ct = wv * 4 + i;               // c-tile (16 channels)
    #pragma unroll
    for (int m2 = 0; m2 < 2; ++m2) {
      const int wb2 = half * 32 + m2 * 16;
      const int wo = wb2 - 8 + q4 * 8;       // A k-octet start (w coord)
      const bool wok = (wo >= 0) && (wo <= 56);
      const u16* vbase = vo + (ct * 16 + l15) * 16384 + wo;  // A: m = l15 (channel)
      f32x4 acc = {0.f, 0.f, 0.f, 0.f};
      for (int dh = 0; dh < 7; ++dh) {
        const int rdh = h + dh - 3;
        if (rdh < 0 || rdh >= 64) continue;  // v row OOB -> zero contribution
        const int rp = (row + dh - 3) * 64;
        short8 af = wok ? *(const short8*)(vbase + rp) : zf;
        short8 bf_ = *(const short8*)(&pb[m2][dh][l15][q4 * 8]);
        acc = __builtin_amdgcn_mfma_f32_16x16x32_bf16(af, bf_, acc, 0, 0, 0);
      }
      // D: row m = channel q4*4+r, col n = pixel l15 -> native [b][c][h][w]
      #pragma unroll
      for (int r = 0; r < 4; ++r)
        out[(b * 256 + ct * 16 + q4 * 4 + r) * 4096 + h * 64 + wb2 + l15] = acc[r];
    }
  }
}

extern "C" void kernel_launch(void* const* d_in, const int* in_sizes, int n_in,
                              void* d_out, int out_size, void* d_ws, size_t ws_size,
                              hipStream_t stream)
{
  const float* x  = (const float*)d_in[0];
  const float* w1 = (const float*)d_in[1];
  const float* w2 = (const float*)d_in[2];
  const float* w3 = (const float*)d_in[3];
  float* out = (float*)d_out;

  // x hi/lo bf16 split lives in d_out (16 MB); consumed by qkv_gemm, then d_out is
  // fully rewritten by attn phase 2 (stream-ordered).
  u16* XTh = (u16*)d_out;
  u16* XTl = XTh + 4194304;

  char* ws = (char*)d_ws;
  u16* qh_ = (u16*)ws;                     // 8 MB bf16 hi(q), pixel-major [pix][c]
  u16* ql_ = (u16*)(ws + (8u  << 20));     // 8 MB bf16 lo(q)
  u16* kh_ = (u16*)(ws + (16u << 20));     // 8 MB bf16 hi(k)
  u16* kl_ = (u16*)(ws + (24u << 20));     // 8 MB bf16 lo(k)
  u16* vo  = (u16*)(ws + (32u << 20));     // 8 MB bf16 v, c-major [c][pix]
  u16* Wh  = (u16*)(ws + (40u << 20));     // 384 KB
  u16* Wl  = Wh + 196608;                  // 384 KB

  split_in<<<dim3(64, 4, 4), 256, 0, stream>>>(x, XTh, XTl);
  wsplit<<<192, 256, 0, stream>>>(w1, w2, w3, Wh, Wl);
  qkv_gemm<<<dim3(128, 2, 3), 256, 0, stream>>>(XTh, XTl, Wh, Wl, qh_, ql_, kh_, kl_, vo);
  attn<<<512, 256, 0, stream>>>(qh_, ql_, kh_, kl_, vo, out);
}